// Round 3
// baseline (307.081 us; speedup 1.0000x reference)
//
#include <hip/hip_runtime.h>

typedef _Float16 f16;
typedef _Float16 f16x4 __attribute__((ext_vector_type(4)));
typedef _Float16 f16x8 __attribute__((ext_vector_type(8)));
typedef float f32x4 __attribute__((ext_vector_type(4)));
typedef int i32x4 __attribute__((ext_vector_type(4)));

#define ALPHA 0.2f
#define NN 8192
#define DD 256
#define INVLN2 1.44269504088896f

// ---------------- K1: Wh = h @ W (f32), plus WhT in fp16 ----------------
// grid 512 blocks x 256 thr; block: 16 rows x 256 cols, K=256; thread: 4x4.
__global__ __launch_bounds__(256) void k1_gemm(const float* __restrict__ h,
                                               const float* __restrict__ W,
                                               float* __restrict__ Wh,
                                               f16* __restrict__ WhT) {
    __shared__ float h_lds[16][256];
    const int t  = threadIdx.x;
    const int i0 = blockIdx.x * 16;

    #pragma unroll
    for (int p = 0; p < 4; ++p) {
        int idx = p * 256 + t;
        int r = idx >> 6;
        int c = (idx & 63) << 2;
        *(float4*)&h_lds[r][c] = *(const float4*)&h[(size_t)(i0 + r) * DD + c];
    }
    __syncthreads();

    const int c0 = (t & 63) << 2;
    const int r0 = (t >> 6) << 2;
    float acc[4][4] = {};

    #pragma unroll 4
    for (int k = 0; k < DD; ++k) {
        float4 w4 = *(const float4*)&W[k * DD + c0];
        #pragma unroll
        for (int r = 0; r < 4; ++r) {
            float hv = h_lds[r0 + r][k];
            acc[r][0] = fmaf(hv, w4.x, acc[r][0]);
            acc[r][1] = fmaf(hv, w4.y, acc[r][1]);
            acc[r][2] = fmaf(hv, w4.z, acc[r][2]);
            acc[r][3] = fmaf(hv, w4.w, acc[r][3]);
        }
    }

    #pragma unroll
    for (int r = 0; r < 4; ++r) {
        float4 v; v.x = acc[r][0]; v.y = acc[r][1]; v.z = acc[r][2]; v.w = acc[r][3];
        *(float4*)&Wh[(size_t)(i0 + r0 + r) * DD + c0] = v;
    }
    #pragma unroll
    for (int c = 0; c < 4; ++c) {
        f16x4 v;
        #pragma unroll
        for (int r = 0; r < 4; ++r) v[r] = (f16)acc[r][c];
        *(f16x4*)&WhT[(size_t)(c0 + c) * NN + i0 + r0] = v;
    }
}

// ---------------- K2: Wh1/Wh2 row dots (pre-scaled by 1/ln2), global max ----------------
__global__ __launch_bounds__(256) void k2_rowdot(const float* __restrict__ Wh,
                                                 const float* __restrict__ a,
                                                 float* __restrict__ Wh1,
                                                 float* __restrict__ Wh2,
                                                 unsigned* __restrict__ maxkey) {
    const int lane = threadIdx.x & 63;
    const int wave = threadIdx.x >> 6;
    const int i = blockIdx.x * 4 + wave;

    float4 v  = *(const float4*)&Wh[(size_t)i * DD + lane * 4];
    float4 a1 = *(const float4*)&a[lane * 4];
    float4 a2 = *(const float4*)&a[DD + lane * 4];
    float s1 = v.x * a1.x + v.y * a1.y + v.z * a1.z + v.w * a1.w;
    float s2 = v.x * a2.x + v.y * a2.y + v.z * a2.z + v.w * a2.w;
    #pragma unroll
    for (int off = 32; off; off >>= 1) {
        s1 += __shfl_down(s1, off);
        s2 += __shfl_down(s2, off);
    }
    if (lane == 0) {
        s1 *= INVLN2;
        s2 *= INVLN2;
        Wh1[i] = s1;
        Wh2[i] = s2;
        unsigned u = __float_as_uint(s2);
        u = (u & 0x80000000u) ? ~u : (u | 0x80000000u);
        atomicMax(maxkey, u);
    }
}

// ---------------- K3: barrier-free fused masked softmax + PV ----------------
// grid 256 x 512 thr (8 waves). Block owns 32 out rows; wave w owns j in
// {s*256 + w*32}. D^T = WhT (A, from global) x P^T (B, in-register).
#define PCOMP(bfrag, ei, adjbit, w2v, wh1v, mv, ssum)      \
    {                                                      \
        float ev = wh1v + w2v;                             \
        ev = fmaxf(ev, ALPHA * ev);                        \
        float pv = exp2f(ev - mv);                         \
        pv = ((adjbit) > 0) ? pv : 0.0f;                   \
        ssum += pv;                                        \
        bfrag[ei] = (f16)pv;                               \
    }

__global__ __launch_bounds__(512, 2) void k3_attn(const int* __restrict__ adj,
                                                  const f16* __restrict__ WhT,
                                                  const float* __restrict__ Wh1,
                                                  const float* __restrict__ Wh2,
                                                  const unsigned* __restrict__ maxkey,
                                                  float* __restrict__ out) {
    __shared__ float Sred[8][32];
    __shared__ float Sfin[32];
    __shared__ __align__(16) float redf[8 * 2 * 64 * 4];   // 16 KB

    const int t    = threadIdx.x;
    const int lane = t & 63;
    const int w    = t >> 6;
    const int i0   = blockIdx.x * 32;
    const int r    = lane & 15;
    const int g8   = (lane >> 4) << 3;

    unsigned mk = *maxkey;
    const float maxW2 = __uint_as_float((mk & 0x80000000u) ? (mk & 0x7fffffffu) : ~mk);

    const float wh1a = Wh1[i0 + r];
    const float wh1b = Wh1[i0 + 16 + r];
    float ta = wh1a + maxW2;
    float tb = wh1b + maxW2;
    const float ma = fmaxf(ta, ALPHA * ta);
    const float mb = fmaxf(tb, ALPHA * tb);

    const int* adjA = adj + (size_t)(i0 + r) * NN;
    const int* adjB = adj + (size_t)(i0 + 16 + r) * NN;

    f32x4 acc0[16], acc1[16];
    #pragma unroll
    for (int nc = 0; nc < 16; ++nc) {
        acc0[nc] = (f32x4){0.f, 0.f, 0.f, 0.f};
        acc1[nc] = (f32x4){0.f, 0.f, 0.f, 0.f};
    }
    float sa = 0.f, sb = 0.f;

    int jb = w * 32;
    i32x4 aA0 = __builtin_nontemporal_load((const i32x4*)(adjA + jb + g8));
    i32x4 aA1 = __builtin_nontemporal_load((const i32x4*)(adjA + jb + g8 + 4));
    i32x4 aB0 = __builtin_nontemporal_load((const i32x4*)(adjB + jb + g8));
    i32x4 aB1 = __builtin_nontemporal_load((const i32x4*)(adjB + jb + g8 + 4));
    float4 w20 = *(const float4*)&Wh2[jb + g8];
    float4 w21 = *(const float4*)&Wh2[jb + g8 + 4];

    for (int s = 0; s < 32; ++s, jb += 256) {
        // ---- prefetch step s+1 (HBM, longest latency — issue first) ----
        i32x4 nA0 = aA0, nA1 = aA1, nB0 = aB0, nB1 = aB1;
        float4 nw0 = w20, nw1 = w21;
        if (s < 31) {
            const int jn = jb + 256 + g8;
            nA0 = __builtin_nontemporal_load((const i32x4*)(adjA + jn));
            nA1 = __builtin_nontemporal_load((const i32x4*)(adjA + jn + 4));
            nB0 = __builtin_nontemporal_load((const i32x4*)(adjB + jn));
            nB1 = __builtin_nontemporal_load((const i32x4*)(adjB + jn + 4));
            nw0 = *(const float4*)&Wh2[jn];
            nw1 = *(const float4*)&Wh2[jn + 4];
        }

        // ---- build P fragments in-register (B operand) ----
        f16x8 b0, b1;
        PCOMP(b0, 0, aA0.x, w20.x, wh1a, ma, sa)
        PCOMP(b0, 1, aA0.y, w20.y, wh1a, ma, sa)
        PCOMP(b0, 2, aA0.z, w20.z, wh1a, ma, sa)
        PCOMP(b0, 3, aA0.w, w20.w, wh1a, ma, sa)
        PCOMP(b0, 4, aA1.x, w21.x, wh1a, ma, sa)
        PCOMP(b0, 5, aA1.y, w21.y, wh1a, ma, sa)
        PCOMP(b0, 6, aA1.z, w21.z, wh1a, ma, sa)
        PCOMP(b0, 7, aA1.w, w21.w, wh1a, ma, sa)
        PCOMP(b1, 0, aB0.x, w20.x, wh1b, mb, sb)
        PCOMP(b1, 1, aB0.y, w20.y, wh1b, mb, sb)
        PCOMP(b1, 2, aB0.z, w20.z, wh1b, mb, sb)
        PCOMP(b1, 3, aB0.w, w20.w, wh1b, mb, sb)
        PCOMP(b1, 4, aB1.x, w21.x, wh1b, mb, sb)
        PCOMP(b1, 5, aB1.y, w21.y, wh1b, mb, sb)
        PCOMP(b1, 6, aB1.z, w21.z, wh1b, mb, sb)
        PCOMP(b1, 7, aB1.w, w21.w, wh1b, mb, sb)

        // ---- A from global (L2-resident WhT) + MFMA, 1-ahead pipelined ----
        const f16* wbase = WhT + jb + g8;
        f16x8 ac = *(const f16x8*)(wbase + (size_t)r * NN);
        #pragma unroll
        for (int nc = 0; nc < 16; ++nc) {
            f16x8 an = ac;
            if (nc < 15) an = *(const f16x8*)(wbase + (size_t)(nc * 16 + 16 + r) * NN);
            acc0[nc] = __builtin_amdgcn_mfma_f32_16x16x32_f16(ac, b0, acc0[nc], 0, 0, 0);
            acc1[nc] = __builtin_amdgcn_mfma_f32_16x16x32_f16(ac, b1, acc1[nc], 0, 0, 0);
            ac = an;
        }

        aA0 = nA0; aA1 = nA1; aB0 = nB0; aB1 = nB1; w20 = nw0; w21 = nw1;
    }

    // ---- row-sum cross-wave reduce ----
    sa += __shfl_xor(sa, 16); sa += __shfl_xor(sa, 32);
    sb += __shfl_xor(sb, 16); sb += __shfl_xor(sb, 32);
    if (lane < 16) {
        Sred[w][lane]      = sa;
        Sred[w][16 + lane] = sb;
    }
    __syncthreads();
    if (t < 32) {
        float s = 0.f;
        #pragma unroll
        for (int q = 0; q < 8; ++q) s += Sred[q][t];
        Sfin[t] = s;
    }

    // ---- accumulator cross-wave reduce + normalize + ELU + store ----
    for (int nc = 0; nc < 16; ++nc) {
        __syncthreads();
        *(f32x4*)&redf[(w * 128 + lane) * 4]      = acc0[nc];
        *(f32x4*)&redf[(w * 128 + 64 + lane) * 4] = acc1[nc];
        __syncthreads();
        float v = 0.f;
        #pragma unroll
        for (int q = 0; q < 8; ++q) v += redf[q * 512 + t];
        int ic = t >> 8;
        int l  = (t >> 2) & 63;
        int i  = ic * 16 + (l & 15);
        int n  = nc * 16 + ((t >> 6) & 3) * 4 + (t & 3);
        float o = v / Sfin[i];
        o = (o > 0.f) ? o : (__expf(o) - 1.f);
        out[(size_t)(i0 + i) * DD + n] = o;
    }
}

extern "C" void kernel_launch(void* const* d_in, const int* in_sizes, int n_in,
                              void* d_out, int out_size, void* d_ws, size_t ws_size,
                              hipStream_t stream) {
    const float* h   = (const float*)d_in[0];
    const int*   adj = (const int*)d_in[1];
    const float* W   = (const float*)d_in[2];
    const float* a   = (const float*)d_in[3];
    float* out = (float*)d_out;

    char* ws = (char*)d_ws;
    float*    Wh     = (float*)ws;                     // 8 MB
    f16*      WhT    = (f16*)(ws + 8388608);           // 4 MB
    float*    Wh1    = (float*)(ws + 12582912);        // 32 KB
    float*    Wh2    = (float*)(ws + 12615680);        // 32 KB
    unsigned* maxkey = (unsigned*)(ws + 12648448);     // 4 B

    hipMemsetAsync(maxkey, 0, 4, stream);
    k1_gemm<<<dim3(512), dim3(256), 0, stream>>>(h, W, Wh, WhT);
    k2_rowdot<<<dim3(2048), dim3(256), 0, stream>>>(Wh, a, Wh1, Wh2, maxkey);
    k3_attn<<<dim3(256), dim3(512), 0, stream>>>(adj, WhT, Wh1, Wh2, maxkey, out);
}